// Round 1
// baseline (1190.662 us; speedup 1.0000x reference)
//
#include <hip/hip_runtime.h>
#include <hip/hip_bf16.h>

#define NB 2
#define NS 2048
#define ND 768
#define NH 12
#define NHD 64
#define N3D 2304

// ---------------------------------------------------------------------------
// Kernel 1: QKV GEMM.  hs[4096x768] @ Wqkv[768x2304] + bqkv
// Epilogue scatters into Q/K/V buffers laid out [B, H, S, HD] (f32),
// folding the softmax scale (1/sqrt(64) = 0.125) into Q.
// 64x64 tile, BK=16, 256 threads, 4x4 micro-tile per thread.
// ---------------------------------------------------------------------------
__global__ __launch_bounds__(256)
void qkv_gemm(const float* __restrict__ A, const float* __restrict__ W,
              const float* __restrict__ bias, float* __restrict__ Qb,
              float* __restrict__ Kb, float* __restrict__ Vb) {
    __shared__ float As[16][68];   // transposed A tile [k][m], pad keeps 16B align
    __shared__ float Bs[16][68];
    const int tx = threadIdx.x & 15;
    const int ty = threadIdx.x >> 4;
    const int m0 = blockIdx.y * 64;
    const int n0 = blockIdx.x * 64;
    const int arow = threadIdx.x >> 2;        // 0..63
    const int ac4  = (threadIdx.x & 3) * 4;   // 0,4,8,12
    const int brow = threadIdx.x >> 4;        // 0..15
    const int bc4  = (threadIdx.x & 15) * 4;  // 0..60
    float acc[4][4] = {};
    for (int k0 = 0; k0 < ND; k0 += 16) {
        float4 a4 = *reinterpret_cast<const float4*>(&A[(m0 + arow) * ND + k0 + ac4]);
        As[ac4 + 0][arow] = a4.x;
        As[ac4 + 1][arow] = a4.y;
        As[ac4 + 2][arow] = a4.z;
        As[ac4 + 3][arow] = a4.w;
        *reinterpret_cast<float4*>(&Bs[brow][bc4]) =
            *reinterpret_cast<const float4*>(&W[(k0 + brow) * N3D + n0 + bc4]);
        __syncthreads();
#pragma unroll
        for (int kk = 0; kk < 16; ++kk) {
            float a[4], b[4];
#pragma unroll
            for (int i = 0; i < 4; ++i) a[i] = As[kk][ty * 4 + i];
#pragma unroll
            for (int j = 0; j < 4; ++j) b[j] = Bs[kk][tx * 4 + j];
#pragma unroll
            for (int i = 0; i < 4; ++i)
#pragma unroll
                for (int j = 0; j < 4; ++j) acc[i][j] += a[i] * b[j];
        }
        __syncthreads();
    }
#pragma unroll
    for (int i = 0; i < 4; ++i) {
        const int m = m0 + ty * 4 + i;
        const int bb = m >> 11;            // S = 2048
        const int ss = m & (NS - 1);
#pragma unroll
        for (int j = 0; j < 4; ++j) {
            const int n = n0 + tx * 4 + j;
            float v = acc[i][j] + bias[n];
            const int sec = n / ND;        // uniform per block (64 | 768)
            const int rem = n - sec * ND;
            const int hh = rem >> 6, dd = rem & 63;
            const size_t idx = (((size_t)bb * NH + hh) * NS + ss) * NHD + dd;
            if (sec == 0)      Qb[idx] = v * 0.125f;  // fold softmax scale
            else if (sec == 1) Kb[idx] = v;
            else               Vb[idx] = v;
        }
    }
}

// ---------------------------------------------------------------------------
// Kernel 2: causal flash attention, f32.
// Grid: (S/32 q-tiles, B*H). 256 threads: thread t -> row r = t>>3 (0..31),
// col-group g = t&7 (8 columns each). Online softmax with 8-lane shuffle
// reductions. K/V staged in 64-row LDS tiles.
// ---------------------------------------------------------------------------
__global__ __launch_bounds__(256)
void flash_attn(const float* __restrict__ Qb, const float* __restrict__ Kb,
                const float* __restrict__ Vb, float* __restrict__ AO) {
    __shared__ float Qs[32][65];   // +1 pad: row-parallel reads hit distinct banks
    __shared__ float Ks[64][65];
    __shared__ float Vs[64][64];
    __shared__ float Ps[32][65];
    const int qt = blockIdx.x;
    const int bh = blockIdx.y;
    const int q0 = qt * 32;
    const int t = threadIdx.x;
    const int r = t >> 3;
    const int g = t & 7;
    const float* Qp = Qb + (size_t)bh * NS * NHD;
    const float* Kp = Kb + (size_t)bh * NS * NHD;
    const float* Vp = Vb + (size_t)bh * NS * NHD;

    {   // stage Q tile [32][64]
        float4 qa = *reinterpret_cast<const float4*>(&Qp[(q0 + r) * NHD + g * 8]);
        float4 qc = *reinterpret_cast<const float4*>(&Qp[(q0 + r) * NHD + g * 8 + 4]);
        Qs[r][g * 8 + 0] = qa.x; Qs[r][g * 8 + 1] = qa.y;
        Qs[r][g * 8 + 2] = qa.z; Qs[r][g * 8 + 3] = qa.w;
        Qs[r][g * 8 + 4] = qc.x; Qs[r][g * 8 + 5] = qc.y;
        Qs[r][g * 8 + 6] = qc.z; Qs[r][g * 8 + 7] = qc.w;
    }   // visibility covered by first in-loop __syncthreads()

    float m_run = -1e30f, l_run = 0.f;
    float o[8] = {0.f, 0.f, 0.f, 0.f, 0.f, 0.f, 0.f, 0.f};
    const int ntiles = (q0 + 31) / 64 + 1;   // causal: kv tiles 0..(q0+31)/64
    const int kr = t >> 2;           // 0..63
    const int kc = (t & 3) * 16;     // 0,16,32,48

    for (int kt = 0; kt < ntiles; ++kt) {
        const int kv0 = kt * 64;
#pragma unroll
        for (int u = 0; u < 16; u += 4) {   // stage K,V tiles [64][64]
            float4 k4 = *reinterpret_cast<const float4*>(&Kp[(kv0 + kr) * NHD + kc + u]);
            Ks[kr][kc + u + 0] = k4.x; Ks[kr][kc + u + 1] = k4.y;
            Ks[kr][kc + u + 2] = k4.z; Ks[kr][kc + u + 3] = k4.w;
            *reinterpret_cast<float4*>(&Vs[kr][kc + u]) =
                *reinterpret_cast<const float4*>(&Vp[(kv0 + kr) * NHD + kc + u]);
        }
        __syncthreads();

        // scores: each thread does 8 dot products of length 64
        float sc[8] = {0.f, 0.f, 0.f, 0.f, 0.f, 0.f, 0.f, 0.f};
#pragma unroll
        for (int d = 0; d < 64; ++d) {
            const float qd = Qs[r][d];
#pragma unroll
            for (int jj = 0; jj < 8; ++jj) sc[jj] += qd * Ks[g * 8 + jj][d];
        }
#pragma unroll
        for (int jj = 0; jj < 8; ++jj)
            if (q0 + r < kv0 + g * 8 + jj) sc[jj] = -1e30f;

        // online softmax (reductions across the 8 lanes sharing a row)
        float tmax = sc[0];
#pragma unroll
        for (int jj = 1; jj < 8; ++jj) tmax = fmaxf(tmax, sc[jj]);
        tmax = fmaxf(tmax, __shfl_xor(tmax, 1));
        tmax = fmaxf(tmax, __shfl_xor(tmax, 2));
        tmax = fmaxf(tmax, __shfl_xor(tmax, 4));
        const float newm = fmaxf(m_run, tmax);
        const float corr = __expf(m_run - newm);
        float psum = 0.f;
#pragma unroll
        for (int jj = 0; jj < 8; ++jj) { sc[jj] = __expf(sc[jj] - newm); psum += sc[jj]; }
        psum += __shfl_xor(psum, 1);
        psum += __shfl_xor(psum, 2);
        psum += __shfl_xor(psum, 4);
        l_run = l_run * corr + psum;
        m_run = newm;
#pragma unroll
        for (int j = 0; j < 8; ++j) o[j] *= corr;
#pragma unroll
        for (int jj = 0; jj < 8; ++jj) Ps[r][g * 8 + jj] = sc[jj];
        __syncthreads();

        // PV: o[j] += sum_k P[r][k] * V[k][g*8+j]
#pragma unroll
        for (int k = 0; k < 64; ++k) {
            const float p = Ps[r][k];
#pragma unroll
            for (int j = 0; j < 8; ++j) o[j] += p * Vs[k][g * 8 + j];
        }
        __syncthreads();   // protect Ks/Vs/Ps before next tile's staging
    }

    const float inv = 1.f / l_run;   // diagonal always present -> l_run > 0
    const int bb = bh / NH, hh = bh - bb * NH;
    float* op = AO + ((size_t)bb * NS + (q0 + r)) * ND + hh * NHD + g * 8;
#pragma unroll
    for (int j = 0; j < 8; ++j) op[j] = o[j] * inv;
}

// ---------------------------------------------------------------------------
// Kernel 3: output projection. AO[4096x768] @ Wout[768x768] + bout -> out
// ---------------------------------------------------------------------------
__global__ __launch_bounds__(256)
void out_gemm(const float* __restrict__ A, const float* __restrict__ W,
              const float* __restrict__ bias, float* __restrict__ C) {
    __shared__ float As[16][68];
    __shared__ float Bs[16][68];
    const int tx = threadIdx.x & 15;
    const int ty = threadIdx.x >> 4;
    const int m0 = blockIdx.y * 64;
    const int n0 = blockIdx.x * 64;
    const int arow = threadIdx.x >> 2;
    const int ac4  = (threadIdx.x & 3) * 4;
    const int brow = threadIdx.x >> 4;
    const int bc4  = (threadIdx.x & 15) * 4;
    float acc[4][4] = {};
    for (int k0 = 0; k0 < ND; k0 += 16) {
        float4 a4 = *reinterpret_cast<const float4*>(&A[(m0 + arow) * ND + k0 + ac4]);
        As[ac4 + 0][arow] = a4.x;
        As[ac4 + 1][arow] = a4.y;
        As[ac4 + 2][arow] = a4.z;
        As[ac4 + 3][arow] = a4.w;
        *reinterpret_cast<float4*>(&Bs[brow][bc4]) =
            *reinterpret_cast<const float4*>(&W[(k0 + brow) * ND + n0 + bc4]);
        __syncthreads();
#pragma unroll
        for (int kk = 0; kk < 16; ++kk) {
            float a[4], b[4];
#pragma unroll
            for (int i = 0; i < 4; ++i) a[i] = As[kk][ty * 4 + i];
#pragma unroll
            for (int j = 0; j < 4; ++j) b[j] = Bs[kk][tx * 4 + j];
#pragma unroll
            for (int i = 0; i < 4; ++i)
#pragma unroll
                for (int j = 0; j < 4; ++j) acc[i][j] += a[i] * b[j];
        }
        __syncthreads();
    }
#pragma unroll
    for (int i = 0; i < 4; ++i) {
        const int m = m0 + ty * 4 + i;
#pragma unroll
        for (int j = 0; j < 4; ++j) {
            const int n = n0 + tx * 4 + j;
            C[(size_t)m * ND + n] = acc[i][j] + bias[n];
        }
    }
}

// ---------------------------------------------------------------------------
extern "C" void kernel_launch(void* const* d_in, const int* in_sizes, int n_in,
                              void* d_out, int out_size, void* d_ws, size_t ws_size,
                              hipStream_t stream) {
    const float* hs   = (const float*)d_in[0];
    const float* Wqkv = (const float*)d_in[1];
    const float* bqkv = (const float*)d_in[2];
    const float* Wout = (const float*)d_in[3];
    const float* bout = (const float*)d_in[4];
    float* out = (float*)d_out;

    const size_t per = (size_t)NB * NH * NS * NHD;  // 3,145,728 floats
    float* Qb = (float*)d_ws;
    float* Kb = Qb + per;
    float* Vb = Kb + per;
    float* AO = Vb + per;   // attention output in [B,S,D] layout

    qkv_gemm<<<dim3(N3D / 64, (NB * NS) / 64), 256, 0, stream>>>(hs, Wqkv, bqkv, Qb, Kb, Vb);
    flash_attn<<<dim3(NS / 32, NB * NH), 256, 0, stream>>>(Qb, Kb, Vb, AO);
    out_gemm<<<dim3(ND / 64, (NB * NS) / 64), 256, 0, stream>>>(AO, Wout, bout, out);
}

// Round 2
// 220.200 us; speedup vs baseline: 5.4072x; 5.4072x over previous
//
#include <hip/hip_runtime.h>
#include <hip/hip_bf16.h>

typedef __attribute__((ext_vector_type(8))) short bf16x8;
typedef __attribute__((ext_vector_type(4))) float f32x4;

#define NB 2
#define NS 2048
#define ND 768
#define NH 12
#define NHD 64
#define N3D 2304
#define NM (NB * NS)   // 4096 rows

__device__ __forceinline__ unsigned short f2bf(float x) {
    union { float f; unsigned u; } v; v.f = x;
    unsigned r = v.u + 0x7FFFu + ((v.u >> 16) & 1u);   // RNE
    return (unsigned short)(r >> 16);
}

// ---------------------------------------------------------------------------
// f32 -> bf16 bulk convert (exact-cover grid, 4 elems/thread)
// ---------------------------------------------------------------------------
__global__ __launch_bounds__(256)
void conv_bf16(const float* __restrict__ in, unsigned short* __restrict__ out) {
    const int i = (blockIdx.x * 256 + threadIdx.x) * 4;
    float4 v = *reinterpret_cast<const float4*>(in + i);
    ushort4 o;
    o.x = f2bf(v.x); o.y = f2bf(v.y); o.z = f2bf(v.z); o.w = f2bf(v.w);
    *reinterpret_cast<ushort4*>(out + i) = o;
}

// ---------------------------------------------------------------------------
// transpose + convert: in [K][N] f32 -> out [N][K] bf16 (32x32 LDS tiles)
// ---------------------------------------------------------------------------
__global__ __launch_bounds__(256)
void transp_conv(const float* __restrict__ in, unsigned short* __restrict__ out,
                 int K, int N) {
    __shared__ float T[32][33];
    const int n0 = blockIdx.x * 32, k0 = blockIdx.y * 32;
    const int r = threadIdx.x >> 3, c4 = (threadIdx.x & 7) * 4;
    float4 v = *reinterpret_cast<const float4*>(&in[(size_t)(k0 + r) * N + n0 + c4]);
    T[r][c4 + 0] = v.x; T[r][c4 + 1] = v.y; T[r][c4 + 2] = v.z; T[r][c4 + 3] = v.w;
    __syncthreads();
    ushort4 o;
    o.x = f2bf(T[c4 + 0][r]); o.y = f2bf(T[c4 + 1][r]);
    o.z = f2bf(T[c4 + 2][r]); o.w = f2bf(T[c4 + 3][r]);
    *reinterpret_cast<ushort4*>(&out[(size_t)(n0 + r) * K + k0 + c4]) = o;
}

// ---------------------------------------------------------------------------
// bf16 MFMA GEMM, K=768, BN=128.  A [M][768] bf16, Bt [N][768] bf16 (n-major).
// 4 waves in 2x2; wave quadrant (BM/2) x 64; 16x16x32 MFMA.
// global_load_lds staging with XOR-swizzled GLOBAL source (LDS stays linear),
// so fragment ds_read_b128 is 2-way (free) within 16-lane phases.
// EPI=0: QKV epilogue -> Q(*0.125)/K as [B,H,S,HD] bf16, V as [B,H,HD,S] bf16.
// EPI=1: plain epilogue -> Co f32 [M][768] + bias.
// ---------------------------------------------------------------------------
template<int BM, int EPI>
__global__ __launch_bounds__(256)
void gemm_k768(const unsigned short* __restrict__ A,
               const unsigned short* __restrict__ Bt,
               const float* __restrict__ bias,
               unsigned short* __restrict__ Qo, unsigned short* __restrict__ Ko,
               unsigned short* __restrict__ Vto, float* __restrict__ Co) {
    __shared__ unsigned short As[BM * 64];
    __shared__ unsigned short Bs[128 * 64];
    const int t = threadIdx.x;
    const int wv = t >> 6, lane = t & 63;
    const int lr = lane & 15, lg = lane >> 4;
    const int wr = wv >> 1, wc = wv & 1;
    const int m0 = blockIdx.y * BM;
    const int n0 = blockIdx.x * 128;
    constexpr int FM = BM / 32;

    f32x4 acc[FM][4];
#pragma unroll
    for (int i = 0; i < FM; ++i)
#pragma unroll
        for (int j = 0; j < 4; ++j) acc[i][j] = (f32x4){0.f, 0.f, 0.f, 0.f};

    const int sr = t >> 3;      // 0..31: staged row within 32-row group
    const int sb = t & 7;       // 8-elem block slot
    for (int k0 = 0; k0 < ND; k0 += 64) {
        __syncthreads();        // prev-iter reads done before overwrite
#pragma unroll
        for (int j = 0; j < BM / 32; ++j) {
            const int row = j * 32 + sr;
            __builtin_amdgcn_global_load_lds(
                (const void*)(A + (size_t)(m0 + row) * ND + k0 + ((sb ^ (row & 7)) * 8)),
                (void*)(As + j * 2048 + wv * 512), 16, 0, 0);
        }
#pragma unroll
        for (int j = 0; j < 4; ++j) {
            const int row = j * 32 + sr;
            __builtin_amdgcn_global_load_lds(
                (const void*)(Bt + (size_t)(n0 + row) * ND + k0 + ((sb ^ (row & 7)) * 8)),
                (void*)(Bs + j * 2048 + wv * 512), 16, 0, 0);
        }
        __syncthreads();        // drains vmcnt -> tiles visible
#pragma unroll
        for (int kc = 0; kc < 2; ++kc) {
            bf16x8 af[FM], bfr[4];
#pragma unroll
            for (int mi = 0; mi < FM; ++mi) {
                const int row = wr * (BM / 2) + mi * 16 + lr;
                af[mi] = *(const bf16x8*)&As[row * 64 + (((kc * 4 + lg) ^ (row & 7)) * 8)];
            }
#pragma unroll
            for (int nj = 0; nj < 4; ++nj) {
                const int row = wc * 64 + nj * 16 + lr;
                bfr[nj] = *(const bf16x8*)&Bs[row * 64 + (((kc * 4 + lg) ^ (row & 7)) * 8)];
            }
#pragma unroll
            for (int mi = 0; mi < FM; ++mi)
#pragma unroll
                for (int nj = 0; nj < 4; ++nj)
                    acc[mi][nj] = __builtin_amdgcn_mfma_f32_16x16x32_bf16(
                        af[mi], bfr[nj], acc[mi][nj], 0, 0, 0);
        }
    }

    if (EPI == 0) {
        const int sec = n0 / ND;      // uniform per block (128 | 768)
#pragma unroll
        for (int mi = 0; mi < FM; ++mi) {
#pragma unroll
            for (int nj = 0; nj < 4; ++nj) {
                const int n = n0 + wc * 64 + nj * 16 + lr;
                const int rem = n - sec * ND;
                const int hh = rem >> 6, dd = rem & 63;
                const float b = bias[n];
#pragma unroll
                for (int r = 0; r < 4; ++r) {
                    const int m = m0 + wr * (BM / 2) + mi * 16 + lg * 4 + r;
                    const int bb = m >> 11, ss = m & (NS - 1);
                    const int bhh = bb * NH + hh;
                    const float v = acc[mi][nj][r] + b;
                    if (sec == 0)
                        Qo[((size_t)bhh * NS + ss) * NHD + dd] = f2bf(v * 0.125f);
                    else if (sec == 1)
                        Ko[((size_t)bhh * NS + ss) * NHD + dd] = f2bf(v);
                    else
                        Vto[((size_t)bhh * NHD + dd) * NS + ss] = f2bf(v);
                }
            }
        }
    } else {
#pragma unroll
        for (int mi = 0; mi < FM; ++mi)
#pragma unroll
            for (int nj = 0; nj < 4; ++nj) {
                const int n = n0 + wc * 64 + nj * 16 + lr;
                const float b = bias[n];
#pragma unroll
                for (int r = 0; r < 4; ++r) {
                    const int m = m0 + wr * (BM / 2) + mi * 16 + lg * 4 + r;
                    Co[(size_t)m * ND + n] = acc[mi][nj][r] + b;
                }
            }
    }
}

// ---------------------------------------------------------------------------
// Causal flash attention, bf16 MFMA 16x16x32.
// Block: 4 waves, 64 q-rows (16/wave), KV tiles of 64.
// Q: [B,H,S,HD] bf16 (pre-scaled).  K: [B,H,S,HD] bf16.  V: [B,H,HD,S] bf16.
// K/Vt staged via global_load_lds (swizzled source); P through per-wave LDS
// (stride 144B -> phase-conflict-free).  qt reversed for load balance.
// ---------------------------------------------------------------------------
__global__ __launch_bounds__(256)
void attn_mfma(const unsigned short* __restrict__ Qg,
               const unsigned short* __restrict__ Kg,
               const unsigned short* __restrict__ Vtg,
               unsigned short* __restrict__ AO) {
    __shared__ unsigned short Ks[64 * 64];
    __shared__ unsigned short Vs[64 * 64];
    __shared__ unsigned short Ps[4][16 * 72];
    const int qt = (int)gridDim.x - 1 - (int)blockIdx.x;   // heavy blocks first
    const int bh = blockIdx.y;
    const int t = threadIdx.x;
    const int w = t >> 6, lane = t & 63;
    const int lr = lane & 15, lg = lane >> 4;
    const int q0 = qt * 64 + w * 16;                       // wave's q base
    const size_t bhoff = (size_t)bh * (NS * NHD);

    // Q fragments in registers (A-operand: row=lr, k=lg*8+i [+32])
    const unsigned short* Qp = Qg + bhoff + (size_t)(q0 + lr) * NHD;
    const bf16x8 qf0 = *(const bf16x8*)(Qp + lg * 8);
    const bf16x8 qf1 = *(const bf16x8*)(Qp + 32 + lg * 8);

    float m_run[4] = {-1e30f, -1e30f, -1e30f, -1e30f};
    float l_run[4] = {0.f, 0.f, 0.f, 0.f};
    f32x4 of[4];
#pragma unroll
    for (int d = 0; d < 4; ++d) of[d] = (f32x4){0.f, 0.f, 0.f, 0.f};

    const unsigned short* Kb = Kg + bhoff;
    const unsigned short* Vb = Vtg + bhoff;
    unsigned short* Pw = Ps[w];
    const int srow = lane >> 3, sblk = lane & 7;
    const int ntiles = qt + 1;

    for (int kt = 0; kt < ntiles; ++kt) {
        const int kv0 = kt * 64;
        // stage K rows / Vt rows (wave w: rows w*16..w*16+15, 2 insts each)
#pragma unroll
        for (int h = 0; h < 2; ++h) {
            const int r = w * 16 + h * 8 + srow;
            __builtin_amdgcn_global_load_lds(
                (const void*)(Kb + (size_t)(kv0 + r) * NHD + ((sblk ^ (r & 7)) * 8)),
                (void*)(Ks + (w * 16 + h * 8) * 64), 16, 0, 0);
            __builtin_amdgcn_global_load_lds(
                (const void*)(Vb + (size_t)r * NS + kv0 + ((sblk ^ (r & 7)) * 8)),
                (void*)(Vs + (w * 16 + h * 8) * 64), 16, 0, 0);
        }
        __syncthreads();

        // S = Q K^T : 4 col-fragments x 2 K-chunks
        f32x4 sf[4];
#pragma unroll
        for (int kf = 0; kf < 4; ++kf) sf[kf] = (f32x4){0.f, 0.f, 0.f, 0.f};
#pragma unroll
        for (int kf = 0; kf < 4; ++kf) {
            const int krow = kf * 16 + lr;
            const bf16x8 b0 = *(const bf16x8*)&Ks[krow * 64 + ((lg ^ (krow & 7)) * 8)];
            const bf16x8 b1 = *(const bf16x8*)&Ks[krow * 64 + (((4 + lg) ^ (krow & 7)) * 8)];
            sf[kf] = __builtin_amdgcn_mfma_f32_16x16x32_bf16(qf0, b0, sf[kf], 0, 0, 0);
            sf[kf] = __builtin_amdgcn_mfma_f32_16x16x32_bf16(qf1, b1, sf[kf], 0, 0, 0);
        }

        if (kt == ntiles - 1) {   // diagonal tile: causal mask
#pragma unroll
            for (int kf = 0; kf < 4; ++kf) {
                const int kcol = kv0 + kf * 16 + lr;
#pragma unroll
                for (int r = 0; r < 4; ++r)
                    if (kcol > q0 + lg * 4 + r) sf[kf][r] = -1e30f;
            }
        }

        // online softmax: reduce over 4 frags + 16 lanes (xor 1,2,4,8)
        float corr[4];
#pragma unroll
        for (int r = 0; r < 4; ++r) {
            float tm = fmaxf(fmaxf(sf[0][r], sf[1][r]), fmaxf(sf[2][r], sf[3][r]));
            tm = fmaxf(tm, __shfl_xor(tm, 1));
            tm = fmaxf(tm, __shfl_xor(tm, 2));
            tm = fmaxf(tm, __shfl_xor(tm, 4));
            tm = fmaxf(tm, __shfl_xor(tm, 8));
            const float nm = fmaxf(m_run[r], tm);
            corr[r] = __expf(m_run[r] - nm);
            m_run[r] = nm;
            float ps = 0.f;
#pragma unroll
            for (int kf = 0; kf < 4; ++kf) {
                sf[kf][r] = __expf(sf[kf][r] - nm);
                ps += sf[kf][r];
            }
            ps += __shfl_xor(ps, 1);
            ps += __shfl_xor(ps, 2);
            ps += __shfl_xor(ps, 4);
            ps += __shfl_xor(ps, 8);
            l_run[r] = l_run[r] * corr[r] + ps;
        }

        // P -> per-wave LDS (bf16), C-layout scatter (phase-conflict-free @144B)
#pragma unroll
        for (int kf = 0; kf < 4; ++kf)
#pragma unroll
            for (int r = 0; r < 4; ++r)
                Pw[(lg * 4 + r) * 72 + kf * 16 + lr] = f2bf(sf[kf][r]);

#pragma unroll
        for (int d = 0; d < 4; ++d)
#pragma unroll
            for (int r = 0; r < 4; ++r) of[d][r] *= corr[r];

        // PV: A = P (from LDS), B = Vt
        const bf16x8 pa0 = *(const bf16x8*)&Pw[lr * 72 + lg * 8];
        const bf16x8 pa1 = *(const bf16x8*)&Pw[lr * 72 + 32 + lg * 8];
#pragma unroll
        for (int dj = 0; dj < 4; ++dj) {
            const int drow = dj * 16 + lr;
            const bf16x8 v0 = *(const bf16x8*)&Vs[drow * 64 + ((lg ^ (drow & 7)) * 8)];
            const bf16x8 v1 = *(const bf16x8*)&Vs[drow * 64 + (((4 + lg) ^ (drow & 7)) * 8)];
            of[dj] = __builtin_amdgcn_mfma_f32_16x16x32_bf16(pa0, v0, of[dj], 0, 0, 0);
            of[dj] = __builtin_amdgcn_mfma_f32_16x16x32_bf16(pa1, v1, of[dj], 0, 0, 0);
        }
        __syncthreads();   // all waves done with Ks/Vs before next stage
    }

    const int bb = bh / NH, hh = bh - bb * NH;
#pragma unroll
    for (int r = 0; r < 4; ++r) {
        const float inv = 1.f / l_run[r];
        const int q = q0 + lg * 4 + r;
        unsigned short* op = AO + ((size_t)(bb * NS + q)) * ND + hh * NHD;
#pragma unroll
        for (int dj = 0; dj < 4; ++dj)
            op[dj * 16 + lr] = f2bf(of[dj][r] * inv);
    }
}

// ---------------------------------------------------------------------------
extern "C" void kernel_launch(void* const* d_in, const int* in_sizes, int n_in,
                              void* d_out, int out_size, void* d_ws, size_t ws_size,
                              hipStream_t stream) {
    const float* hs   = (const float*)d_in[0];
    const float* Wqkv = (const float*)d_in[1];
    const float* bqkv = (const float*)d_in[2];
    const float* Wout = (const float*)d_in[3];
    const float* bout = (const float*)d_in[4];
    float* out = (float*)d_out;

    char* wp = (char*)d_ws;
    unsigned short* hsb = (unsigned short*)wp; wp += (size_t)NM * ND * 2;
    unsigned short* W1t = (unsigned short*)wp; wp += (size_t)N3D * ND * 2;
    unsigned short* W2t = (unsigned short*)wp; wp += (size_t)ND * ND * 2;
    const size_t per = (size_t)NB * NH * NS * NHD;   // 3,145,728 elems
    unsigned short* Qb  = (unsigned short*)wp; wp += per * 2;
    unsigned short* Kb  = (unsigned short*)wp; wp += per * 2;
    unsigned short* Vtb = (unsigned short*)wp; wp += per * 2;
    unsigned short* AOb = (unsigned short*)wp; wp += per * 2;

    conv_bf16<<<(NM * ND) / 1024, 256, 0, stream>>>(hs, hsb);
    transp_conv<<<dim3(N3D / 32, ND / 32), 256, 0, stream>>>(Wqkv, W1t, ND, N3D);
    transp_conv<<<dim3(ND / 32, ND / 32), 256, 0, stream>>>(Wout, W2t, ND, ND);

    gemm_k768<128, 0><<<dim3(N3D / 128, NM / 128), 256, 0, stream>>>(
        hsb, W1t, bqkv, Qb, Kb, Vtb, nullptr);

    attn_mfma<<<dim3(NS / 64, NB * NH), 256, 0, stream>>>(Qb, Kb, Vtb, AOb);

    gemm_k768<64, 1><<<dim3(ND / 128, NM / 64), 256, 0, stream>>>(
        AOb, W2t, bout, nullptr, nullptr, nullptr, out);
}

// Round 3
// 203.809 us; speedup vs baseline: 5.8420x; 1.0804x over previous
//
#include <hip/hip_runtime.h>
#include <hip/hip_bf16.h>

typedef __attribute__((ext_vector_type(8))) short bf16x8;
typedef __attribute__((ext_vector_type(4))) float f32x4;
typedef __attribute__((ext_vector_type(4))) unsigned int u32x4;

#define NB 2
#define NS 2048
#define ND 768
#define NH 12
#define NHD 64
#define N3D 2304
#define NM (NB * NS)   // 4096 rows

__device__ __forceinline__ unsigned short f2bf(float x) {
    union { float f; unsigned u; } v; v.f = x;
    unsigned r = v.u + 0x7FFFu + ((v.u >> 16) & 1u);   // RNE
    return (unsigned short)(r >> 16);
}

__device__ __forceinline__ unsigned cvt_pk_bf16(float lo, float hi) {
    unsigned r;
    asm volatile("v_cvt_pk_bf16_f32 %0, %1, %2" : "=v"(r) : "v"(lo), "v"(hi));
    return r;   // D.bf16[0] = lo, D.bf16[1] = hi
}

// ---------------------------------------------------------------------------
// f32 -> bf16 bulk convert
// ---------------------------------------------------------------------------
__global__ __launch_bounds__(256)
void conv_bf16(const float* __restrict__ in, unsigned short* __restrict__ out) {
    const int i = (blockIdx.x * 256 + threadIdx.x) * 4;
    float4 v = *reinterpret_cast<const float4*>(in + i);
    ushort4 o;
    o.x = f2bf(v.x); o.y = f2bf(v.y); o.z = f2bf(v.z); o.w = f2bf(v.w);
    *reinterpret_cast<ushort4*>(out + i) = o;
}

// ---------------------------------------------------------------------------
// transpose + convert: in [K][N] f32 -> out [N][K] bf16 (32x32 LDS tiles)
// ---------------------------------------------------------------------------
__global__ __launch_bounds__(256)
void transp_conv(const float* __restrict__ in, unsigned short* __restrict__ out,
                 int K, int N) {
    __shared__ float T[32][33];
    const int n0 = blockIdx.x * 32, k0 = blockIdx.y * 32;
    const int r = threadIdx.x >> 3, c4 = (threadIdx.x & 7) * 4;
    float4 v = *reinterpret_cast<const float4*>(&in[(size_t)(k0 + r) * N + n0 + c4]);
    T[r][c4 + 0] = v.x; T[r][c4 + 1] = v.y; T[r][c4 + 2] = v.z; T[r][c4 + 3] = v.w;
    __syncthreads();
    ushort4 o;
    o.x = f2bf(T[c4 + 0][r]); o.y = f2bf(T[c4 + 1][r]);
    o.z = f2bf(T[c4 + 2][r]); o.w = f2bf(T[c4 + 3][r]);
    *reinterpret_cast<ushort4*>(&out[(size_t)(n0 + r) * K + k0 + c4]) = o;
}

// ---------------------------------------------------------------------------
// bf16 MFMA GEMM, K=768, BN=128 (unchanged from round 2 except Q scale now
// folds log2(e) so attention can use exp2 directly).
// ---------------------------------------------------------------------------
template<int BM, int EPI>
__global__ __launch_bounds__(256)
void gemm_k768(const unsigned short* __restrict__ A,
               const unsigned short* __restrict__ Bt,
               const float* __restrict__ bias,
               unsigned short* __restrict__ Qo, unsigned short* __restrict__ Ko,
               unsigned short* __restrict__ Vto, float* __restrict__ Co) {
    __shared__ unsigned short As[BM * 64];
    __shared__ unsigned short Bs[128 * 64];
    const int t = threadIdx.x;
    const int wv = t >> 6, lane = t & 63;
    const int lr = lane & 15, lg = lane >> 4;
    const int wr = wv >> 1, wc = wv & 1;
    const int m0 = blockIdx.y * BM;
    const int n0 = blockIdx.x * 128;
    constexpr int FM = BM / 32;

    f32x4 acc[FM][4];
#pragma unroll
    for (int i = 0; i < FM; ++i)
#pragma unroll
        for (int j = 0; j < 4; ++j) acc[i][j] = (f32x4){0.f, 0.f, 0.f, 0.f};

    const int sr = t >> 3;
    const int sb = t & 7;
    for (int k0 = 0; k0 < ND; k0 += 64) {
        __syncthreads();
#pragma unroll
        for (int j = 0; j < BM / 32; ++j) {
            const int row = j * 32 + sr;
            __builtin_amdgcn_global_load_lds(
                (const void*)(A + (size_t)(m0 + row) * ND + k0 + ((sb ^ (row & 7)) * 8)),
                (void*)(As + j * 2048 + wv * 512), 16, 0, 0);
        }
#pragma unroll
        for (int j = 0; j < 4; ++j) {
            const int row = j * 32 + sr;
            __builtin_amdgcn_global_load_lds(
                (const void*)(Bt + (size_t)(n0 + row) * ND + k0 + ((sb ^ (row & 7)) * 8)),
                (void*)(Bs + j * 2048 + wv * 512), 16, 0, 0);
        }
        __syncthreads();
#pragma unroll
        for (int kc = 0; kc < 2; ++kc) {
            bf16x8 af[FM], bfr[4];
#pragma unroll
            for (int mi = 0; mi < FM; ++mi) {
                const int row = wr * (BM / 2) + mi * 16 + lr;
                af[mi] = *(const bf16x8*)&As[row * 64 + (((kc * 4 + lg) ^ (row & 7)) * 8)];
            }
#pragma unroll
            for (int nj = 0; nj < 4; ++nj) {
                const int row = wc * 64 + nj * 16 + lr;
                bfr[nj] = *(const bf16x8*)&Bs[row * 64 + (((kc * 4 + lg) ^ (row & 7)) * 8)];
            }
#pragma unroll
            for (int mi = 0; mi < FM; ++mi)
#pragma unroll
                for (int nj = 0; nj < 4; ++nj)
                    acc[mi][nj] = __builtin_amdgcn_mfma_f32_16x16x32_bf16(
                        af[mi], bfr[nj], acc[mi][nj], 0, 0, 0);
        }
    }

    if (EPI == 0) {
        const int sec = n0 / ND;
#pragma unroll
        for (int mi = 0; mi < FM; ++mi) {
#pragma unroll
            for (int nj = 0; nj < 4; ++nj) {
                const int n = n0 + wc * 64 + nj * 16 + lr;
                const int rem = n - sec * ND;
                const int hh = rem >> 6, dd = rem & 63;
                const float b = bias[n];
#pragma unroll
                for (int r = 0; r < 4; ++r) {
                    const int m = m0 + wr * (BM / 2) + mi * 16 + lg * 4 + r;
                    const int bb = m >> 11, ss = m & (NS - 1);
                    const int bhh = bb * NH + hh;
                    const float v = acc[mi][nj][r] + b;
                    if (sec == 0)   // 0.125 * log2(e): attention works in exp2 domain
                        Qo[((size_t)bhh * NS + ss) * NHD + dd] = f2bf(v * 0.18033688011112042f);
                    else if (sec == 1)
                        Ko[((size_t)bhh * NS + ss) * NHD + dd] = f2bf(v);
                    else
                        Vto[((size_t)bhh * NHD + dd) * NS + ss] = f2bf(v);
                }
            }
        }
    } else {
#pragma unroll
        for (int mi = 0; mi < FM; ++mi)
#pragma unroll
            for (int nj = 0; nj < 4; ++nj) {
                const int n = n0 + wc * 64 + nj * 16 + lr;
                const float b = bias[n];
#pragma unroll
                for (int r = 0; r < 4; ++r) {
                    const int m = m0 + wr * (BM / 2) + mi * 16 + lg * 4 + r;
                    Co[(size_t)m * ND + n] = acc[mi][nj][r] + b;
                }
            }
    }
}

// ---------------------------------------------------------------------------
// Causal flash attention, swapped-QK^T bf16 MFMA.
//   S^T = mfma(A=K, B=Q)  -> lane owns 16 kv of one q-row (q = lane&15)
//   softmax: 15 in-reg fmax + 2 shfl (xor16/32); exp2 domain (Q pre-scaled)
//   P^T rebuilt in-register: 8 cvt_pk + 4 shfl_xor(16), kv-permutation sigma
//   shared with the Vt A-operand block reads (no P LDS buffer).
//   O^T = mfma(A=Vt, B=P^T); K/V double-buffered via global_load_lds.
// ---------------------------------------------------------------------------
__global__ __launch_bounds__(256)
void attn_mfma(const unsigned short* __restrict__ Qg,
               const unsigned short* __restrict__ Kg,
               const unsigned short* __restrict__ Vtg,
               unsigned short* __restrict__ AO) {
    __shared__ unsigned short Ks[2][64 * 64];
    __shared__ unsigned short Vs[2][64 * 64];
    const int qt = (int)gridDim.x - 1 - (int)blockIdx.x;   // heavy blocks first
    const int bh = blockIdx.y;
    const int t = threadIdx.x;
    const int w = t >> 6, lane = t & 63;
    const int lr = lane & 15, lg = lane >> 4;
    const int lgp = lg & 1;                                // lane-group parity
    const int qrow = qt * 64 + w * 16 + lr;
    const size_t bhoff = (size_t)bh * (NS * NHD);

    // Q as MFMA B-operand: lane supplies Q[q=lr][d = 32c + lg*8 + i]
    const unsigned short* Qp = Qg + bhoff + (size_t)qrow * NHD;
    const bf16x8 qB0 = *(const bf16x8*)(Qp + lg * 8);
    const bf16x8 qB1 = *(const bf16x8*)(Qp + 32 + lg * 8);

    float m_run = -1e30f, l_run = 0.f;
    f32x4 of[4];   // O^T frag fA: row d = fA*16 + lg*4 + r, col q = lr
#pragma unroll
    for (int f = 0; f < 4; ++f) of[f] = (f32x4){0.f, 0.f, 0.f, 0.f};

    const unsigned short* Kb = Kg + bhoff;
    const unsigned short* Vb = Vtg + bhoff;
    const int srow = lane >> 3, sblk = lane & 7;
    const int ntiles = qt + 1;
    // Vt A-operand block index per chunk: kv block = 4c + bswz(lg)
    const int bswz = ((lg & 1) << 1) | (lg >> 1);

#define STAGE(buf, kv0)                                                          \
    {                                                                            \
        _Pragma("unroll")                                                        \
        for (int h = 0; h < 2; ++h) {                                            \
            const int rr = w * 16 + h * 8 + srow;                                \
            __builtin_amdgcn_global_load_lds(                                    \
                (const void*)(Kb + (size_t)((kv0) + rr) * NHD + ((sblk ^ (rr & 7)) * 8)), \
                (void*)(Ks[buf] + (w * 16 + h * 8) * 64), 16, 0, 0);             \
            __builtin_amdgcn_global_load_lds(                                    \
                (const void*)(Vb + (size_t)rr * NS + (kv0) + ((sblk ^ (rr & 7)) * 8)),    \
                (void*)(Vs[buf] + (w * 16 + h * 8) * 64), 16, 0, 0);             \
        }                                                                        \
    }

    STAGE(0, 0);
    for (int kt = 0; kt < ntiles; ++kt) {
        __syncthreads();               // tile kt visible; prev-tile reads done
        if (kt + 1 < ntiles) STAGE((kt + 1) & 1, (kt + 1) * 64);
        const unsigned short* Kc = Ks[kt & 1];
        const unsigned short* Vc = Vs[kt & 1];
        const int kv0 = kt * 64;

        // ---- S^T = K Q^T : 4 kv-frags x 2 d-chunks ----
        f32x4 sf[4];
#pragma unroll
        for (int f = 0; f < 4; ++f) sf[f] = (f32x4){0.f, 0.f, 0.f, 0.f};
#pragma unroll
        for (int f = 0; f < 4; ++f) {
            const int krow = f * 16 + lr;
            const bf16x8 a0 = *(const bf16x8*)&Kc[krow * 64 + ((lg ^ (krow & 7)) * 8)];
            const bf16x8 a1 = *(const bf16x8*)&Kc[krow * 64 + (((4 + lg) ^ (krow & 7)) * 8)];
            sf[f] = __builtin_amdgcn_mfma_f32_16x16x32_bf16(a0, qB0, sf[f], 0, 0, 0);
            sf[f] = __builtin_amdgcn_mfma_f32_16x16x32_bf16(a1, qB1, sf[f], 0, 0, 0);
        }

        if (kt == ntiles - 1) {        // causal mask, diagonal tile only
            const int thr = qrow - kv0;
#pragma unroll
            for (int f = 0; f < 4; ++f)
#pragma unroll
                for (int r = 0; r < 4; ++r)
                    if (f * 16 + lg * 4 + r > thr) sf[f][r] = -1e30f;
        }

        // ---- online softmax (exp2 domain) ----
        float tm = fmaxf(fmaxf(fmaxf(sf[0][0], sf[0][1]), fmaxf(sf[0][2], sf[0][3])),
                         fmaxf(fmaxf(sf[1][0], sf[1][1]), fmaxf(sf[1][2], sf[1][3])));
        tm = fmaxf(tm, fmaxf(fmaxf(fmaxf(sf[2][0], sf[2][1]), fmaxf(sf[2][2], sf[2][3])),
                             fmaxf(fmaxf(sf[3][0], sf[3][1]), fmaxf(sf[3][2], sf[3][3]))));
        tm = fmaxf(tm, __shfl_xor(tm, 16));
        tm = fmaxf(tm, __shfl_xor(tm, 32));
        const float nm = fmaxf(m_run, tm);
        const float corr = exp2f(m_run - nm);
        m_run = nm;
        float ps = 0.f;
#pragma unroll
        for (int f = 0; f < 4; ++f)
#pragma unroll
            for (int r = 0; r < 4; ++r) {
                sf[f][r] = exp2f(sf[f][r] - nm);
                ps += sf[f][r];
            }
        ps += __shfl_xor(ps, 16);
        ps += __shfl_xor(ps, 32);
        l_run = l_run * corr + ps;
#pragma unroll
        for (int f = 0; f < 4; ++f)
#pragma unroll
            for (int r = 0; r < 4; ++r) of[f][r] *= corr;

        // ---- pack P^T and build B-frags (kv-permutation sigma) ----
        unsigned P2[4][2];
#pragma unroll
        for (int f = 0; f < 4; ++f) {
            P2[f][0] = cvt_pk_bf16(sf[f][0], sf[f][1]);
            P2[f][1] = cvt_pk_bf16(sf[f][2], sf[f][3]);
        }
        bf16x8 pb[2];
#pragma unroll
        for (int c = 0; c < 2; ++c) {
            // send partner-needed frag (its dest f = 2c + 1 - own parity)
            const unsigned s0 = lgp ? P2[2 * c][0] : P2[2 * c + 1][0];
            const unsigned s1 = lgp ? P2[2 * c][1] : P2[2 * c + 1][1];
            const unsigned r0 = (unsigned)__shfl_xor((int)s0, 16);
            const unsigned r1 = (unsigned)__shfl_xor((int)s1, 16);
            const unsigned o0 = lgp ? P2[2 * c + 1][0] : P2[2 * c][0];
            const unsigned o1 = lgp ? P2[2 * c + 1][1] : P2[2 * c][1];
            // even lg: own = low half of kv-block; odd lg: own = high half
            u32x4 wv;
            wv[0] = lgp ? r0 : o0;
            wv[1] = lgp ? r1 : o1;
            wv[2] = lgp ? o0 : r0;
            wv[3] = lgp ? o1 : r1;
            pb[c] = __builtin_bit_cast(bf16x8, wv);
        }

        // ---- O^T += Vt P^T ----
#pragma unroll
        for (int fA = 0; fA < 4; ++fA) {
            const int drow = fA * 16 + lr;
#pragma unroll
            for (int c = 0; c < 2; ++c) {
                const int blk = 4 * c + bswz;
                const bf16x8 va = *(const bf16x8*)&Vc[drow * 64 + ((blk ^ (drow & 7)) * 8)];
                of[fA] = __builtin_amdgcn_mfma_f32_16x16x32_bf16(va, pb[c], of[fA], 0, 0, 0);
            }
        }
    }
#undef STAGE

    // ---- epilogue: O^T rows contiguous in d -> 4x 8B stores ----
    const int bb = bh / NH, hh = bh - bb * NH;
    const float inv = 1.f / l_run;
    unsigned short* op = AO + ((size_t)(bb * NS + qrow)) * ND + hh * NHD;
#pragma unroll
    for (int fA = 0; fA < 4; ++fA) {
        ushort4 o4;
        o4.x = f2bf(of[fA][0] * inv);
        o4.y = f2bf(of[fA][1] * inv);
        o4.z = f2bf(of[fA][2] * inv);
        o4.w = f2bf(of[fA][3] * inv);
        *reinterpret_cast<ushort4*>(op + fA * 16 + lg * 4) = o4;
    }
}

// ---------------------------------------------------------------------------
extern "C" void kernel_launch(void* const* d_in, const int* in_sizes, int n_in,
                              void* d_out, int out_size, void* d_ws, size_t ws_size,
                              hipStream_t stream) {
    const float* hs   = (const float*)d_in[0];
    const float* Wqkv = (const float*)d_in[1];
    const float* bqkv = (const float*)d_in[2];
    const float* Wout = (const float*)d_in[3];
    const float* bout = (const float*)d_in[4];
    float* out = (float*)d_out;

    char* wp = (char*)d_ws;
    unsigned short* hsb = (unsigned short*)wp; wp += (size_t)NM * ND * 2;
    unsigned short* W1t = (unsigned short*)wp; wp += (size_t)N3D * ND * 2;
    unsigned short* W2t = (unsigned short*)wp; wp += (size_t)ND * ND * 2;
    const size_t per = (size_t)NB * NH * NS * NHD;
    unsigned short* Qb  = (unsigned short*)wp; wp += per * 2;
    unsigned short* Kb  = (unsigned short*)wp; wp += per * 2;
    unsigned short* Vtb = (unsigned short*)wp; wp += per * 2;
    unsigned short* AOb = (unsigned short*)wp; wp += per * 2;

    conv_bf16<<<(NM * ND) / 1024, 256, 0, stream>>>(hs, hsb);
    transp_conv<<<dim3(N3D / 32, ND / 32), 256, 0, stream>>>(Wqkv, W1t, ND, N3D);
    transp_conv<<<dim3(ND / 32, ND / 32), 256, 0, stream>>>(Wout, W2t, ND, ND);

    gemm_k768<128, 0><<<dim3(N3D / 128, NM / 128), 256, 0, stream>>>(
        hsb, W1t, bqkv, Qb, Kb, Vtb, nullptr);

    attn_mfma<<<dim3(NS / 64, NB * NH), 256, 0, stream>>>(Qb, Kb, Vtb, AOb);

    gemm_k768<64, 1><<<dim3(ND / 128, NM / 64), 256, 0, stream>>>(
        AOb, W2t, bout, nullptr, nullptr, nullptr, out);
}

// Round 4
// 191.340 us; speedup vs baseline: 6.2228x; 1.0652x over previous
//
#include <hip/hip_runtime.h>
#include <hip/hip_bf16.h>

typedef __attribute__((ext_vector_type(8))) short bf16x8;
typedef __attribute__((ext_vector_type(4))) float f32x4;
typedef __attribute__((ext_vector_type(4))) unsigned int u32x4;

#define NB 2
#define NS 2048
#define ND 768
#define NH 12
#define NHD 64
#define N3D 2304
#define NM (NB * NS)   // 4096 rows

__device__ __forceinline__ unsigned short f2bf(float x) {
    union { float f; unsigned u; } v; v.f = x;
    unsigned r = v.u + 0x7FFFu + ((v.u >> 16) & 1u);   // RNE
    return (unsigned short)(r >> 16);
}

__device__ __forceinline__ unsigned cvt_pk_bf16(float lo, float hi) {
    unsigned r;
    asm volatile("v_cvt_pk_bf16_f32 %0, %1, %2" : "=v"(r) : "v"(lo), "v"(hi));
    return r;   // D.bf16[0] = lo, D.bf16[1] = hi
}

// ---------------------------------------------------------------------------
// f32 -> bf16 bulk convert
// ---------------------------------------------------------------------------
__global__ __launch_bounds__(256)
void conv_bf16(const float* __restrict__ in, unsigned short* __restrict__ out) {
    const int i = (blockIdx.x * 256 + threadIdx.x) * 4;
    float4 v = *reinterpret_cast<const float4*>(in + i);
    ushort4 o;
    o.x = f2bf(v.x); o.y = f2bf(v.y); o.z = f2bf(v.z); o.w = f2bf(v.w);
    *reinterpret_cast<ushort4*>(out + i) = o;
}

// ---------------------------------------------------------------------------
// transpose + convert: in [K][N] f32 -> out [N][K] bf16 (32x32 LDS tiles)
// ---------------------------------------------------------------------------
__global__ __launch_bounds__(256)
void transp_conv(const float* __restrict__ in, unsigned short* __restrict__ out,
                 int K, int N) {
    __shared__ float T[32][33];
    const int n0 = blockIdx.x * 32, k0 = blockIdx.y * 32;
    const int r = threadIdx.x >> 3, c4 = (threadIdx.x & 7) * 4;
    float4 v = *reinterpret_cast<const float4*>(&in[(size_t)(k0 + r) * N + n0 + c4]);
    T[r][c4 + 0] = v.x; T[r][c4 + 1] = v.y; T[r][c4 + 2] = v.z; T[r][c4 + 3] = v.w;
    __syncthreads();
    ushort4 o;
    o.x = f2bf(T[c4 + 0][r]); o.y = f2bf(T[c4 + 1][r]);
    o.z = f2bf(T[c4 + 2][r]); o.w = f2bf(T[c4 + 3][r]);
    *reinterpret_cast<ushort4*>(&out[(size_t)(n0 + r) * K + k0 + c4]) = o;
}

// ---------------------------------------------------------------------------
// bf16 MFMA GEMM, K=768, BN=128, double-buffered 2-phase prefetch:
// one barrier per K-step; next tile's global_load_lds fly under compute.
// ---------------------------------------------------------------------------
template<int BM, int EPI>
__global__ __launch_bounds__(256)
void gemm_k768(const unsigned short* __restrict__ A,
               const unsigned short* __restrict__ Bt,
               const float* __restrict__ bias,
               unsigned short* __restrict__ Qo, unsigned short* __restrict__ Ko,
               unsigned short* __restrict__ Vto, float* __restrict__ Co) {
    __shared__ unsigned short As[2][BM * 64];
    __shared__ unsigned short Bs[2][128 * 64];
    const int t = threadIdx.x;
    const int wv = t >> 6, lane = t & 63;
    const int lr = lane & 15, lg = lane >> 4;
    const int wr = wv >> 1, wc = wv & 1;
    const int m0 = blockIdx.y * BM;
    const int n0 = blockIdx.x * 128;
    constexpr int FM = BM / 32;

    f32x4 acc[FM][4];
#pragma unroll
    for (int i = 0; i < FM; ++i)
#pragma unroll
        for (int j = 0; j < 4; ++j) acc[i][j] = (f32x4){0.f, 0.f, 0.f, 0.f};

    const int sr = t >> 3;
    const int sb = t & 7;

#define GSTAGE(buf, k0)                                                          \
    {                                                                            \
        _Pragma("unroll")                                                        \
        for (int jj = 0; jj < BM / 32; ++jj) {                                   \
            const int row = jj * 32 + sr;                                        \
            __builtin_amdgcn_global_load_lds(                                    \
                (const void*)(A + (size_t)(m0 + row) * ND + (k0) + ((sb ^ (row & 7)) * 8)), \
                (void*)(As[buf] + jj * 2048 + wv * 512), 16, 0, 0);              \
        }                                                                        \
        _Pragma("unroll")                                                        \
        for (int jj = 0; jj < 4; ++jj) {                                         \
            const int row = jj * 32 + sr;                                        \
            __builtin_amdgcn_global_load_lds(                                    \
                (const void*)(Bt + (size_t)(n0 + row) * ND + (k0) + ((sb ^ (row & 7)) * 8)), \
                (void*)(Bs[buf] + jj * 2048 + wv * 512), 16, 0, 0);              \
        }                                                                        \
    }

    GSTAGE(0, 0);
    for (int ki = 0; ki < ND / 64; ++ki) {
        __syncthreads();                       // tile ki ready; prev buf free
        if (ki + 1 < ND / 64) GSTAGE((ki + 1) & 1, (ki + 1) * 64);
        const unsigned short* Ac = As[ki & 1];
        const unsigned short* Bc = Bs[ki & 1];
#pragma unroll
        for (int kc = 0; kc < 2; ++kc) {
            bf16x8 af[FM], bfr[4];
#pragma unroll
            for (int mi = 0; mi < FM; ++mi) {
                const int row = wr * (BM / 2) + mi * 16 + lr;
                af[mi] = *(const bf16x8*)&Ac[row * 64 + (((kc * 4 + lg) ^ (row & 7)) * 8)];
            }
#pragma unroll
            for (int nj = 0; nj < 4; ++nj) {
                const int row = wc * 64 + nj * 16 + lr;
                bfr[nj] = *(const bf16x8*)&Bc[row * 64 + (((kc * 4 + lg) ^ (row & 7)) * 8)];
            }
#pragma unroll
            for (int mi = 0; mi < FM; ++mi)
#pragma unroll
                for (int nj = 0; nj < 4; ++nj)
                    acc[mi][nj] = __builtin_amdgcn_mfma_f32_16x16x32_bf16(
                        af[mi], bfr[nj], acc[mi][nj], 0, 0, 0);
        }
    }
#undef GSTAGE

    if (EPI == 0) {
        const int sec = n0 / ND;
#pragma unroll
        for (int mi = 0; mi < FM; ++mi) {
#pragma unroll
            for (int nj = 0; nj < 4; ++nj) {
                const int n = n0 + wc * 64 + nj * 16 + lr;
                const int rem = n - sec * ND;
                const int hh = rem >> 6, dd = rem & 63;
                const float b = bias[n];
#pragma unroll
                for (int r = 0; r < 4; ++r) {
                    const int m = m0 + wr * (BM / 2) + mi * 16 + lg * 4 + r;
                    const int bb = m >> 11, ss = m & (NS - 1);
                    const int bhh = bb * NH + hh;
                    const float v = acc[mi][nj][r] + b;
                    if (sec == 0)   // 0.125 * log2(e): attention works in exp2 domain
                        Qo[((size_t)bhh * NS + ss) * NHD + dd] = f2bf(v * 0.18033688011112042f);
                    else if (sec == 1)
                        Ko[((size_t)bhh * NS + ss) * NHD + dd] = f2bf(v);
                    else
                        Vto[((size_t)bhh * NHD + dd) * NS + ss] = f2bf(v);
                }
            }
        }
    } else {
#pragma unroll
        for (int mi = 0; mi < FM; ++mi)
#pragma unroll
            for (int nj = 0; nj < 4; ++nj) {
                const int n = n0 + wc * 64 + nj * 16 + lr;
                const float b = bias[n];
#pragma unroll
                for (int r = 0; r < 4; ++r) {
                    const int m = m0 + wr * (BM / 2) + mi * 16 + lg * 4 + r;
                    Co[(size_t)m * ND + n] = acc[mi][nj][r] + b;
                }
            }
    }
}

// ---------------------------------------------------------------------------
// Causal flash attention, swapped-QK^T bf16 MFMA, KVBLK=128.
//   Balanced (qt,bh) block map: period-256 CU slots get qt offsets {0,11,22}
//   -> per-CU kv-tile sums ~equal (was 3..96, 32x disparity).
//   Deferred l: per-lane partial sum, cross-lane reduce once at the end.
//   Skip-rescale when __all(tm <= m_run) (exact).
// ---------------------------------------------------------------------------
__global__ __launch_bounds__(256)
void attn_mfma(const unsigned short* __restrict__ Qg,
               const unsigned short* __restrict__ Kg,
               const unsigned short* __restrict__ Vtg,
               unsigned short* __restrict__ AO) {
    __shared__ unsigned short Ks[2][128 * 64];
    __shared__ unsigned short Vs[2][64 * 128];
    const int n = blockIdx.x;               // 768 blocks
    const int jj3 = n >> 8, cc8 = n & 255;
    const int qt = ((cc8 & 31) + jj3 * 11) & 31;
    const int bh = jj3 * 8 + (cc8 >> 5);
    const int t = threadIdx.x;
    const int w = t >> 6, lane = t & 63;
    const int lr = lane & 15, lg = lane >> 4;
    const int lgp = lg & 1;
    const int qrow = qt * 64 + w * 16 + lr;
    const size_t bhoff = (size_t)bh * (NS * NHD);

    // Q as MFMA B-operand: lane supplies Q[q=lr][d = 32c + lg*8 + i]
    const unsigned short* Qp = Qg + bhoff + (size_t)qrow * NHD;
    const bf16x8 qB0 = *(const bf16x8*)(Qp + lg * 8);
    const bf16x8 qB1 = *(const bf16x8*)(Qp + 32 + lg * 8);

    float m_run = -1e30f, l_part = 0.f;
    f32x4 of[4];
#pragma unroll
    for (int f = 0; f < 4; ++f) of[f] = (f32x4){0.f, 0.f, 0.f, 0.f};

    const unsigned short* Kb = Kg + bhoff;
    const unsigned short* Vb = Vtg + bhoff;
    const int ksrow = lane >> 3, ksblk = lane & 7;    // K staging (128x64)
    const int vsrow = lane >> 4, vsblk = lane & 15;   // Vt staging (64x128)
    const int ntiles = (qt + 2) >> 1;                 // KVBLK=128
    const int bswz = ((lg & 1) << 1) | (lg >> 1);     // kv-block sigma

#define STAGE(buf, kv0)                                                           \
    {                                                                             \
        _Pragma("unroll")                                                         \
        for (int h = 0; h < 4; ++h) {                                             \
            const int rr = w * 32 + h * 8 + ksrow;                                \
            __builtin_amdgcn_global_load_lds(                                     \
                (const void*)(Kb + (size_t)((kv0) + rr) * NHD + ((ksblk ^ (rr & 7)) * 8)),  \
                (void*)(Ks[buf] + (w * 32 + h * 8) * 64), 16, 0, 0);              \
            const int vr = w * 16 + h * 4 + vsrow;                                \
            __builtin_amdgcn_global_load_lds(                                     \
                (const void*)(Vb + (size_t)vr * NS + (kv0) + ((vsblk ^ (vr & 7)) * 8)),     \
                (void*)(Vs[buf] + (w * 16 + h * 4) * 128), 16, 0, 0);             \
        }                                                                         \
    }

    STAGE(0, 0);
    for (int kt = 0; kt < ntiles; ++kt) {
        __syncthreads();               // tile kt visible; prev-tile reads done
        if (kt + 1 < ntiles) STAGE((kt + 1) & 1, (kt + 1) * 128);
        const unsigned short* Kc = Ks[kt & 1];
        const unsigned short* Vc = Vs[kt & 1];
        const int kv0 = kt * 128;

        // ---- S^T = K Q^T : 8 kv-frags x 2 d-chunks ----
        f32x4 sf[8];
#pragma unroll
        for (int f = 0; f < 8; ++f) sf[f] = (f32x4){0.f, 0.f, 0.f, 0.f};
        __builtin_amdgcn_s_setprio(1);
#pragma unroll
        for (int f = 0; f < 8; ++f) {
            const int krow = f * 16 + lr;
            const bf16x8 a0 = *(const bf16x8*)&Kc[krow * 64 + ((lg ^ (krow & 7)) * 8)];
            const bf16x8 a1 = *(const bf16x8*)&Kc[krow * 64 + (((4 + lg) ^ (krow & 7)) * 8)];
            sf[f] = __builtin_amdgcn_mfma_f32_16x16x32_bf16(a0, qB0, sf[f], 0, 0, 0);
            sf[f] = __builtin_amdgcn_mfma_f32_16x16x32_bf16(a1, qB1, sf[f], 0, 0, 0);
        }
        __builtin_amdgcn_s_setprio(0);

        if (kt == ntiles - 1) {        // causal mask, last tile only
            const int thr = qrow - kv0;
#pragma unroll
            for (int f = 0; f < 8; ++f)
#pragma unroll
                for (int r = 0; r < 4; ++r)
                    if (f * 16 + lg * 4 + r > thr) sf[f][r] = -1e30f;
        }

        // ---- online softmax (exp2 domain), deferred-l ----
        float tm = -1e30f;
#pragma unroll
        for (int f = 0; f < 8; ++f)
            tm = fmaxf(tm, fmaxf(fmaxf(sf[f][0], sf[f][1]), fmaxf(sf[f][2], sf[f][3])));
        tm = fmaxf(tm, __shfl_xor(tm, 16));
        tm = fmaxf(tm, __shfl_xor(tm, 32));
        if (!__all(tm <= m_run)) {
            const float nm = fmaxf(m_run, tm);
            const float corr = exp2f(m_run - nm);
            m_run = nm;
            l_part *= corr;
#pragma unroll
            for (int f = 0; f < 4; ++f)
#pragma unroll
                for (int r = 0; r < 4; ++r) of[f][r] *= corr;
        }
#pragma unroll
        for (int f = 0; f < 8; ++f)
#pragma unroll
            for (int r = 0; r < 4; ++r) {
                sf[f][r] = exp2f(sf[f][r] - m_run);
                l_part += sf[f][r];
            }

        // ---- pack P^T (sigma kv-permutation, partner exchange over xor16) ----
        bf16x8 pb[4];
#pragma unroll
        for (int c = 0; c < 4; ++c) {
            const unsigned A0 = cvt_pk_bf16(sf[2 * c][0], sf[2 * c][1]);
            const unsigned A1 = cvt_pk_bf16(sf[2 * c][2], sf[2 * c][3]);
            const unsigned B0 = cvt_pk_bf16(sf[2 * c + 1][0], sf[2 * c + 1][1]);
            const unsigned B1 = cvt_pk_bf16(sf[2 * c + 1][2], sf[2 * c + 1][3]);
            const unsigned s0 = lgp ? A0 : B0;
            const unsigned s1 = lgp ? A1 : B1;
            const unsigned r0 = (unsigned)__shfl_xor((int)s0, 16);
            const unsigned r1 = (unsigned)__shfl_xor((int)s1, 16);
            const unsigned o0 = lgp ? B0 : A0;
            const unsigned o1 = lgp ? B1 : A1;
            u32x4 wvv;
            wvv[0] = lgp ? r0 : o0;
            wvv[1] = lgp ? r1 : o1;
            wvv[2] = lgp ? o0 : r0;
            wvv[3] = lgp ? o1 : r1;
            pb[c] = __builtin_bit_cast(bf16x8, wvv);
        }

        // ---- O^T += Vt P^T ----
        __builtin_amdgcn_s_setprio(1);
#pragma unroll
        for (int fA = 0; fA < 4; ++fA) {
            const int drow = fA * 16 + lr;
#pragma unroll
            for (int c = 0; c < 4; ++c) {
                const int blk = 4 * c + bswz;
                const bf16x8 va = *(const bf16x8*)&Vc[drow * 128 + ((blk ^ (drow & 7)) * 8)];
                of[fA] = __builtin_amdgcn_mfma_f32_16x16x32_bf16(va, pb[c], of[fA], 0, 0, 0);
            }
        }
        __builtin_amdgcn_s_setprio(0);
    }
#undef STAGE

    // ---- final l reduce + epilogue (O^T rows contiguous in d) ----
    l_part += __shfl_xor(l_part, 16);
    l_part += __shfl_xor(l_part, 32);
    const float inv = 1.f / l_part;
    const int bb = bh / NH, hh = bh - bb * NH;
    unsigned short* op = AO + ((size_t)(bb * NS + qrow)) * ND + hh * NHD;
#pragma unroll
    for (int fA = 0; fA < 4; ++fA) {
        ushort4 o4;
        o4.x = f2bf(of[fA][0] * inv);
        o4.y = f2bf(of[fA][1] * inv);
        o4.z = f2bf(of[fA][2] * inv);
        o4.w = f2bf(of[fA][3] * inv);
        *reinterpret_cast<ushort4*>(op + fA * 16 + lg * 4) = o4;
    }
}

// ---------------------------------------------------------------------------
extern "C" void kernel_launch(void* const* d_in, const int* in_sizes, int n_in,
                              void* d_out, int out_size, void* d_ws, size_t ws_size,
                              hipStream_t stream) {
    const float* hs   = (const float*)d_in[0];
    const float* Wqkv = (const float*)d_in[1];
    const float* bqkv = (const float*)d_in[2];
    const float* Wout = (const float*)d_in[3];
    const float* bout = (const float*)d_in[4];
    float* out = (float*)d_out;

    char* wp = (char*)d_ws;
    unsigned short* hsb = (unsigned short*)wp; wp += (size_t)NM * ND * 2;
    unsigned short* W1t = (unsigned short*)wp; wp += (size_t)N3D * ND * 2;
    unsigned short* W2t = (unsigned short*)wp; wp += (size_t)ND * ND * 2;
    const size_t per = (size_t)NB * NH * NS * NHD;
    unsigned short* Qb  = (unsigned short*)wp; wp += per * 2;
    unsigned short* Kb  = (unsigned short*)wp; wp += per * 2;
    unsigned short* Vtb = (unsigned short*)wp; wp += per * 2;
    unsigned short* AOb = (unsigned short*)wp; wp += per * 2;

    conv_bf16<<<(NM * ND) / 1024, 256, 0, stream>>>(hs, hsb);
    transp_conv<<<dim3(N3D / 32, ND / 32), 256, 0, stream>>>(Wqkv, W1t, ND, N3D);
    transp_conv<<<dim3(ND / 32, ND / 32), 256, 0, stream>>>(Wout, W2t, ND, ND);

    gemm_k768<128, 0><<<dim3(N3D / 128, NM / 128), 256, 0, stream>>>(
        hsb, W1t, bqkv, Qb, Kb, Vtb, nullptr);

    attn_mfma<<<dim3(NS / 64 * NB * NH), 256, 0, stream>>>(Qb, Kb, Vtb, AOb);

    gemm_k768<64, 1><<<dim3(ND / 128, NM / 64), 256, 0, stream>>>(
        AOb, W2t, bout, nullptr, nullptr, nullptr, out);
}